// Round 10
// baseline (288.255 us; speedup 1.0000x reference)
//
#include <hip/hip_runtime.h>
#include <hip/hip_bf16.h>
#include <math.h>

#define BB 16
#define LL 4096
#define DD 1024
#define OD 64
#define NP 2016
#define NC 256
#define VD 64
#define NCHUNK 64
#define LCH (LL / NCHUNK)
#define TT 16      // tokens per MFMA tile
#define TPB 128    // tokens per block (main kernel) -> 512 blocks = 2/CU
#define NROW (NP + VD)   // 2080: params rows + vq_proj_in rows

typedef __attribute__((ext_vector_type(8))) short bf16x8;
typedef __attribute__((ext_vector_type(4))) float f32x4;

__device__ __forceinline__ int triu_idx(int r, int c) {
  return r * 63 - (r * (r - 1)) / 2 + (c - r - 1);
}

__device__ __forceinline__ unsigned short f2bf(float f) {
  unsigned int u = __float_as_uint(f);
  u += 0x7fffu + ((u >> 16) & 1u);
  return (unsigned short)(u >> 16);
}

// ---------------- Kernel 1a: partial sums over L chunks ----------------
__global__ void k_partial(const float* __restrict__ x, float* __restrict__ partial) {
  const int b = blockIdx.y, ch = blockIdx.x, tid = threadIdx.x;
  const float4* xp = (const float4*)(x + ((size_t)b * LL + (size_t)ch * LCH) * DD) + tid;
  float4 s = make_float4(0.f, 0.f, 0.f, 0.f);
  #pragma unroll 8
  for (int l = 0; l < LCH; ++l) {
    float4 v = xp[(size_t)l * (DD / 4)];
    s.x += v.x; s.y += v.y; s.z += v.z; s.w += v.w;
  }
  ((float4*)(partial + ((size_t)(b * NCHUNK + ch)) * DD))[tid] = s;
}

// ---------------- Kernel 1b: finalize mean ----------------
__global__ void k_mean(const float* __restrict__ partial, float* __restrict__ hm) {
  const int b = blockIdx.x, tid = threadIdx.x;
  float4 s = make_float4(0.f, 0.f, 0.f, 0.f);
  for (int c = 0; c < NCHUNK; ++c) {
    float4 v = ((const float4*)(partial + ((size_t)(b * NCHUNK + c)) * DD))[tid];
    s.x += v.x; s.y += v.y; s.z += v.z; s.w += v.w;
  }
  const float inv = 1.0f / (float)LL;
  s.x *= inv; s.y *= inv; s.z *= inv; s.w *= inv;
  ((float4*)(hm + (size_t)b * DD))[tid] = s;
}

// ------- Kernel 2a: 2080-row GEMV — params rows (opw/opb) + vqi rows (viw/vib) ----
__global__ void k_params(const float* __restrict__ hm,
                         const float* __restrict__ opw, const float* __restrict__ opb,
                         const float* __restrict__ viw, const float* __restrict__ vib,
                         float* __restrict__ params, float* __restrict__ vqi_g) {
  const int wave = threadIdx.x >> 6, lane = threadIdx.x & 63;
  const int p = blockIdx.x * 4 + wave;  // 0..2079
  if (p >= NROW) return;
  const bool isvq = (p >= NP);
  const float* wr = isvq ? (viw + (size_t)(p - NP) * DD) : (opw + (size_t)p * DD);
  float acc[BB];
  #pragma unroll
  for (int b = 0; b < BB; ++b) acc[b] = 0.f;
  for (int i = 0; i < DD; i += 64) {
    const float wv = wr[i + lane];
    #pragma unroll
    for (int b = 0; b < BB; ++b) acc[b] = fmaf(wv, hm[b * DD + i + lane], acc[b]);
  }
  const float bias = isvq ? vib[p - NP] : opb[p];
  #pragma unroll
  for (int b = 0; b < BB; ++b) {
    float v = acc[b];
    #pragma unroll
    for (int mk = 32; mk; mk >>= 1) v += __shfl_xor(v, mk, 64);
    if (lane == 0) {
      if (isvq) vqi_g[(size_t)b * VD + (p - NP)] = v + bias;
      else      params[(size_t)b * NP + p] = v + bias;
    }
  }
}

// ------- Kernel 2b (fused, parallel): grid (17, 16) ----------------------
// blockIdx.x < 16: one MTB e-chunk; G recomputed redundantly in LDS (cheap:
// ~2K FMA/thread) — keeps 256-block parallelism (R8 lesson: never collapse
// to 16 blocks). blockIdx.x == 16: VQ argmax + cvec for batch b.
__global__ void k_post(const float* __restrict__ params, const float* __restrict__ vqi_g,
                       const float* __restrict__ cb, const float* __restrict__ oob,
                       const float* __restrict__ vow, const float* __restrict__ vob,
                       const float* __restrict__ omix_p, const float* __restrict__ vmix_p,
                       const float* __restrict__ oow,
                       unsigned short* __restrict__ MTB, float* __restrict__ cvec) {
  const int b = blockIdx.y, tid = threadIdx.x;
  const float omix = omix_p[0];
  if (blockIdx.x < 16) {
    __shared__ float om[OD][OD + 1];
    __shared__ float om2[OD][OD + 1];
    __shared__ float gs[OD][OD + 1];
    __shared__ float wl[64][65];
    const int eb = blockIdx.x * 64;
    const float* par = params + (size_t)b * NP;
    for (int e2 = tid; e2 < OD * OD; e2 += 256) {
      int i = e2 >> 6, j = e2 & 63;
      float v = 0.f;
      if (i < j) v = par[triu_idx(i, j)];
      else if (i > j) v = -par[triu_idx(j, i)];
      om[i][j] = v;
    }
    for (int e2 = tid; e2 < 64 * 64; e2 += 256)
      wl[e2 >> 6][e2 & 63] = oow[(size_t)(eb + (e2 >> 6)) * 64 + (e2 & 63)];
    __syncthreads();
    for (int e2 = tid; e2 < OD * OD; e2 += 256) {
      int i = e2 >> 6, j = e2 & 63;
      float s = 0.f;
      #pragma unroll 8
      for (int k = 0; k < OD; ++k) s = fmaf(om[i][k], om[k][j], s);
      om2[i][j] = s;
    }
    __syncthreads();
    for (int e2 = tid; e2 < OD * OD; e2 += 256) {
      int i = e2 >> 6, j = e2 & 63;
      float s3 = 0.f;
      #pragma unroll 8
      for (int k = 0; k < OD; ++k) s3 = fmaf(om2[i][k], om[k][j], s3);
      gs[i][j] = om[i][j] + 0.5f * om2[i][j] + (1.f / 6.f) * s3 + (i == j ? 1.f : 0.f);
    }
    __syncthreads();
    for (int o = tid; o < 4096; o += 256) {
      int el = o >> 6, d = o & 63;
      float s = 0.f;
      #pragma unroll
      for (int k = 0; k < 64; ++k) s = fmaf(gs[d][k], wl[el][k], s);
      MTB[((size_t)b * DD + eb + el) * OD + d] = f2bf(omix * s);
    }
  } else {
    __shared__ float vqi[VD];
    __shared__ float sc[NC];
    __shared__ int si[NC];
    __shared__ float cd[VD];
    __shared__ float nv_s;
    if (tid < VD) vqi[tid] = vqi_g[(size_t)b * VD + tid];
    __syncthreads();
    if (tid == 0) {
      float s = 0.f;
      for (int k = 0; k < VD; ++k) s += vqi[k] * vqi[k];
      nv_s = fmaxf(sqrtf(s), 1e-12f);
    }
    __syncthreads();
    {
      const float* cr = cb + (size_t)tid * VD;
      float dot = 0.f, ssq = 0.f;
      #pragma unroll 8
      for (int k = 0; k < VD; ++k) { float cvv = cr[k]; dot = fmaf(cvv, vqi[k], dot); ssq = fmaf(cvv, cvv, ssq); }
      float ncn = fmaxf(sqrtf(ssq), 1e-12f);
      sc[tid] = dot / (nv_s * ncn);
      si[tid] = tid;
    }
    __syncthreads();
    for (int s = 128; s > 0; s >>= 1) {
      if (tid < s) {
        float a = sc[tid], b2 = sc[tid + s];
        int ia = si[tid], ib = si[tid + s];
        if (b2 > a || (b2 == a && ib < ia)) { sc[tid] = b2; si[tid] = ib; }
      }
      __syncthreads();
    }
    const int best = si[0];
    if (tid < VD) cd[tid] = cb[(size_t)best * VD + tid];
    __syncthreads();
    const float vmix = vmix_p[0];
    for (int e = tid; e < DD; e += 256) {
      float a = vob[e];
      const float* wr = vow + (size_t)e * VD;
      #pragma unroll 8
      for (int k = 0; k < VD; ++k) a = fmaf(cd[k], wr[k], a);
      cvec[(size_t)b * DD + e] = fmaf(omix, oob[e], vmix * a);
    }
  }
}

// ---------------- Kernel 3: MFMA main pass (v5: TPB=128, 2 blocks/CU) --------
// Keep VGPR <= 64 so two 1024-thr blocks co-reside (32 waves/CU): cross-block
// overlap hides per-tile barrier drains. Structure otherwise = R8 v4.
__global__ __launch_bounds__(1024)
void k_mfma(const float* __restrict__ x, const unsigned short* __restrict__ MTB,
            const float* __restrict__ cvec, const float* __restrict__ nw,
            float* __restrict__ out) {
  const int b = blockIdx.y;
  const int Tblk = blockIdx.x * TPB;
  const int tid = threadIdx.x;
  const int w = tid >> 6, lane = tid & 63;
  const int c = lane & 15, g = lane >> 4;
  const int ebase = w * 64;

  __shared__ unsigned short xh[2][TT][72];  // 144B rows: 64 d + 8 pad
  __shared__ float red[2][TT][20];          // padded rows: 2-way banks max

  bf16x8 bf[4][2];
  {
    const unsigned short* mp = MTB + ((size_t)b * DD + ebase + c) * OD + g * 8;
    #pragma unroll
    for (int et = 0; et < 4; ++et) {
      #pragma unroll
      for (int ks = 0; ks < 2; ++ks)
        bf[et][ks] = *(const bf16x8*)(mp + (size_t)et * 16 * OD + ks * 32);
    }
  }
  float ce_r[4], nw_r[4];
  #pragma unroll
  for (int et = 0; et < 4; ++et) {
    ce_r[et] = cvec[(size_t)b * DD + ebase + et * 16 + c];
    nw_r[et] = nw[ebase + et * 16 + c];
  }

  const size_t xrow = ((size_t)b * LL + Tblk) * DD;
  const int stok = tid >> 4, sd0 = (tid & 15) * 4;
  const bool stager = (tid < 256);

  if (stager) {
    const float4 v = *(const float4*)(x + xrow + (size_t)stok * DD + sd0);
    unsigned int lo = (unsigned int)f2bf(v.x) | ((unsigned int)f2bf(v.y) << 16);
    unsigned int hi = (unsigned int)f2bf(v.z) | ((unsigned int)f2bf(v.w) << 16);
    *(uint2*)((char*)&xh[0][0][0] + stok * 144 + sd0 * 2) = make_uint2(lo, hi);
  }
  __syncthreads();

  int cur = 0, par = 0;
  for (int tt = 0; tt < TPB; tt += TT) {
    if (stager && tt + TT < TPB) {
      const float4 v = *(const float4*)(x + xrow + (size_t)(tt + TT + stok) * DD + sd0);
      unsigned int lo = (unsigned int)f2bf(v.x) | ((unsigned int)f2bf(v.y) << 16);
      unsigned int hi = (unsigned int)f2bf(v.z) | ((unsigned int)f2bf(v.w) << 16);
      *(uint2*)((char*)&xh[cur ^ 1][0][0] + stok * 144 + sd0 * 2) = make_uint2(lo, hi);
    }

    const char* xbB = (const char*)&xh[cur][0][0];
    bf16x8 af0 = *(const bf16x8*)(xbB + c * 144 + 0 * 64 + g * 16);
    bf16x8 af1 = *(const bf16x8*)(xbB + c * 144 + 1 * 64 + g * 16);

    float res[4][4];
    #pragma unroll
    for (int et = 0; et < 4; ++et) {
      #pragma unroll
      for (int r = 0; r < 4; ++r)
        res[et][r] = x[xrow + (size_t)(tt + g * 4 + r) * DD + ebase + et * 16 + c];
    }

    f32x4 acc[4];
    #pragma unroll
    for (int et = 0; et < 4; ++et) {
      acc[et] = (f32x4){0.f, 0.f, 0.f, 0.f};
      acc[et] = __builtin_amdgcn_mfma_f32_16x16x32_bf16(af0, bf[et][0], acc[et], 0, 0, 0);
      acc[et] = __builtin_amdgcn_mfma_f32_16x16x32_bf16(af1, bf[et][1], acc[et], 0, 0, 0);
    }

    float p[4] = {0.f, 0.f, 0.f, 0.f};
    #pragma unroll
    for (int et = 0; et < 4; ++et) {
      #pragma unroll
      for (int r = 0; r < 4; ++r) {
        const float y = res[et][r] + acc[et][r] + ce_r[et];
        acc[et][r] = y;
        p[r] = fmaf(y, y, p[r]);
      }
    }
    #pragma unroll
    for (int mk = 1; mk < 16; mk <<= 1) {
      #pragma unroll
      for (int r = 0; r < 4; ++r) p[r] += __shfl_xor(p[r], mk, 64);
    }
    if (c == 0) {
      #pragma unroll
      for (int r = 0; r < 4; ++r) red[par][g * 4 + r][w] = p[r];
    }
    __syncthreads();   // the ONLY barrier: publishes red[par] AND xh[cur^1]

    float sc_r[4];
    #pragma unroll
    for (int r = 0; r < 4; ++r) {
      const float4* rp = (const float4*)&red[par][g * 4 + r][0];
      const float4 s0 = rp[0], s1 = rp[1], s2 = rp[2], s3 = rp[3];
      const float s = s0.x + s0.y + s0.z + s0.w + s1.x + s1.y + s1.z + s1.w
                    + s2.x + s2.y + s2.z + s2.w + s3.x + s3.y + s3.z + s3.w;
      sc_r[r] = rsqrtf(s * (1.f / (float)DD) + 1e-6f);
    }
    #pragma unroll
    for (int et = 0; et < 4; ++et) {
      #pragma unroll
      for (int r = 0; r < 4; ++r) {
        out[xrow + (size_t)(tt + g * 4 + r) * DD + ebase + et * 16 + c] =
            acc[et][r] * sc_r[r] * nw_r[et];
      }
    }
    cur ^= 1; par ^= 1;
  }
}

extern "C" void kernel_launch(void* const* d_in, const int* in_sizes, int n_in,
                              void* d_out, int out_size, void* d_ws, size_t ws_size,
                              hipStream_t stream) {
  (void)in_sizes; (void)n_in; (void)out_size; (void)ws_size;
  const float* x    = (const float*)d_in[0];
  const float* opw  = (const float*)d_in[1];
  const float* opb  = (const float*)d_in[2];
  const float* oow  = (const float*)d_in[3];
  const float* oob  = (const float*)d_in[4];
  const float* viw  = (const float*)d_in[5];
  const float* vib  = (const float*)d_in[6];
  const float* vow  = (const float*)d_in[7];
  const float* vob  = (const float*)d_in[8];
  const float* cb   = (const float*)d_in[9];
  const float* omix = (const float*)d_in[10];
  const float* vmix = (const float*)d_in[11];
  const float* nw   = (const float*)d_in[12];
  float* out = (float*)d_out;

  float* ws      = (float*)d_ws;
  float* partial = ws;                 // 1048576 floats
  float* hm      = ws + 1048576;       // 16384
  float* params  = ws + 1064960;       // 32256
  float* vqi_g   = ws + 1097216;       // 1024
  unsigned short* MTB = (unsigned short*)(ws + 1098240);  // 1M ushort
  float* cvec    = ws + 1622528;       // 16384

  k_partial<<<dim3(NCHUNK, BB), 256, 0, stream>>>(x, partial);
  k_mean<<<BB, 256, 0, stream>>>(partial, hm);
  k_params<<<NROW / 4, 256, 0, stream>>>(hm, opw, opb, viw, vib, params, vqi_g);
  k_post<<<dim3(17, BB), 256, 0, stream>>>(params, vqi_g, cb, oob, vow, vob,
                                           omix, vmix, oow, MTB, cvec);
  k_mfma<<<dim3(LL / TPB, BB), 1024, 0, stream>>>(x, MTB, cvec, nw, out);
}

// Round 11
// 252.277 us; speedup vs baseline: 1.1426x; 1.1426x over previous
//
#include <hip/hip_runtime.h>
#include <hip/hip_bf16.h>
#include <math.h>

#define BB 16
#define LL 4096
#define DD 1024
#define OD 64
#define NP 2016
#define NC 256
#define VD 64
#define NCHUNK 64
#define LCH (LL / NCHUNK)
#define TT 16      // tokens per MFMA tile
#define TPB 256    // tokens per block (main kernel) -> 256 blocks = 1/CU (R9 best)
#define NROW (NP + VD)   // 2080: params rows + vq_proj_in rows

typedef __attribute__((ext_vector_type(8))) short bf16x8;
typedef __attribute__((ext_vector_type(4))) float f32x4;

__device__ __forceinline__ int triu_idx(int r, int c) {
  return r * 63 - (r * (r - 1)) / 2 + (c - r - 1);
}

__device__ __forceinline__ unsigned short f2bf(float f) {
  unsigned int u = __float_as_uint(f);
  u += 0x7fffu + ((u >> 16) & 1u);
  return (unsigned short)(u >> 16);
}

// ---------------- Kernel 1a: partial sums over L chunks ----------------
__global__ void k_partial(const float* __restrict__ x, float* __restrict__ partial) {
  const int b = blockIdx.y, ch = blockIdx.x, tid = threadIdx.x;
  const float4* xp = (const float4*)(x + ((size_t)b * LL + (size_t)ch * LCH) * DD) + tid;
  float4 s = make_float4(0.f, 0.f, 0.f, 0.f);
  #pragma unroll 8
  for (int l = 0; l < LCH; ++l) {
    float4 v = xp[(size_t)l * (DD / 4)];
    s.x += v.x; s.y += v.y; s.z += v.z; s.w += v.w;
  }
  ((float4*)(partial + ((size_t)(b * NCHUNK + ch)) * DD))[tid] = s;
}

// ---------------- Kernel 1b: finalize mean ----------------
__global__ void k_mean(const float* __restrict__ partial, float* __restrict__ hm) {
  const int b = blockIdx.x, tid = threadIdx.x;
  float4 s = make_float4(0.f, 0.f, 0.f, 0.f);
  for (int c = 0; c < NCHUNK; ++c) {
    float4 v = ((const float4*)(partial + ((size_t)(b * NCHUNK + c)) * DD))[tid];
    s.x += v.x; s.y += v.y; s.z += v.z; s.w += v.w;
  }
  const float inv = 1.0f / (float)LL;
  s.x *= inv; s.y *= inv; s.z *= inv; s.w *= inv;
  ((float4*)(hm + (size_t)b * DD))[tid] = s;
}

// ------- Kernel 2a: 2080-row GEMV — params rows (opw/opb) + vqi rows (viw/vib) ----
__global__ void k_params(const float* __restrict__ hm,
                         const float* __restrict__ opw, const float* __restrict__ opb,
                         const float* __restrict__ viw, const float* __restrict__ vib,
                         float* __restrict__ params, float* __restrict__ vqi_g) {
  const int wave = threadIdx.x >> 6, lane = threadIdx.x & 63;
  const int p = blockIdx.x * 4 + wave;  // 0..2079
  if (p >= NROW) return;
  const bool isvq = (p >= NP);
  const float* wr = isvq ? (viw + (size_t)(p - NP) * DD) : (opw + (size_t)p * DD);
  float acc[BB];
  #pragma unroll
  for (int b = 0; b < BB; ++b) acc[b] = 0.f;
  for (int i = 0; i < DD; i += 64) {
    const float wv = wr[i + lane];
    #pragma unroll
    for (int b = 0; b < BB; ++b) acc[b] = fmaf(wv, hm[b * DD + i + lane], acc[b]);
  }
  const float bias = isvq ? vib[p - NP] : opb[p];
  #pragma unroll
  for (int b = 0; b < BB; ++b) {
    float v = acc[b];
    #pragma unroll
    for (int mk = 32; mk; mk >>= 1) v += __shfl_xor(v, mk, 64);
    if (lane == 0) {
      if (isvq) vqi_g[(size_t)b * VD + (p - NP)] = v + bias;
      else      params[(size_t)b * NP + p] = v + bias;
    }
  }
}

// ---------------- Kernel 2b: per-batch omega -> G, VQ argmax, cvec --------
__global__ void k_perb(const float* __restrict__ params, const float* __restrict__ vqi_g,
                       const float* __restrict__ cb,
                       const float* __restrict__ oob, const float* __restrict__ vow,
                       const float* __restrict__ vob,
                       const float* __restrict__ omix_p, const float* __restrict__ vmix_p,
                       float* __restrict__ Gout, float* __restrict__ cvec) {
  const int b = blockIdx.x, tid = threadIdx.x;
  __shared__ float om[OD][OD + 1];
  __shared__ float om2[OD][OD + 1];
  __shared__ float vqi[VD];
  __shared__ float sc[NC];
  __shared__ int si[NC];
  __shared__ float cd[VD];
  __shared__ float nv_s;
  const float* par = params + (size_t)b * NP;

  if (tid < VD) vqi[tid] = vqi_g[(size_t)b * VD + tid];
  for (int e2 = tid; e2 < OD * OD; e2 += 256) {
    int i = e2 >> 6, j = e2 & 63;
    float v = 0.f;
    if (i < j) v = par[triu_idx(i, j)];
    else if (i > j) v = -par[triu_idx(j, i)];
    om[i][j] = v;
  }
  __syncthreads();
  if (tid == 0) {
    float s = 0.f;
    for (int k = 0; k < VD; ++k) s += vqi[k] * vqi[k];
    nv_s = fmaxf(sqrtf(s), 1e-12f);
  }
  for (int e2 = tid; e2 < OD * OD; e2 += 256) {
    int i = e2 >> 6, j = e2 & 63;
    float s = 0.f;
    #pragma unroll 8
    for (int k = 0; k < OD; ++k) s = fmaf(om[i][k], om[k][j], s);
    om2[i][j] = s;
  }
  __syncthreads();
  for (int e2 = tid; e2 < OD * OD; e2 += 256) {
    int i = e2 >> 6, j = e2 & 63;
    float s3 = 0.f;
    #pragma unroll 8
    for (int k = 0; k < OD; ++k) s3 = fmaf(om2[i][k], om[k][j], s3);
    float gv = om[i][j] + 0.5f * om2[i][j] + (1.f / 6.f) * s3 + (i == j ? 1.f : 0.f);
    Gout[(size_t)b * OD * OD + e2] = gv;
  }
  {
    const float* cr = cb + (size_t)tid * VD;
    float dot = 0.f, ssq = 0.f;
    #pragma unroll 8
    for (int k = 0; k < VD; ++k) { float cvv = cr[k]; dot = fmaf(cvv, vqi[k], dot); ssq = fmaf(cvv, cvv, ssq); }
    float ncn = fmaxf(sqrtf(ssq), 1e-12f);
    sc[tid] = dot / (nv_s * ncn);
    si[tid] = tid;
  }
  __syncthreads();
  for (int s = 128; s > 0; s >>= 1) {
    if (tid < s) {
      float a = sc[tid], b2 = sc[tid + s];
      int ia = si[tid], ib = si[tid + s];
      if (b2 > a || (b2 == a && ib < ia)) { sc[tid] = b2; si[tid] = ib; }
    }
    __syncthreads();
  }
  const int best = si[0];
  if (tid < VD) cd[tid] = cb[(size_t)best * VD + tid];
  __syncthreads();
  const float omix = omix_p[0], vmix = vmix_p[0];
  for (int e = tid; e < DD; e += 256) {
    float a = vob[e];
    const float* wr = vow + (size_t)e * VD;
    #pragma unroll 8
    for (int k = 0; k < VD; ++k) a = fmaf(cd[k], wr[k], a);
    cvec[(size_t)b * DD + e] = fmaf(omix, oob[e], vmix * a);
  }
}

// ------- Kernel 2c: MTB[b][e][d] = bf16( omix * sum_k G[d][k]*oow[e][k] ) ----
__global__ void k_MTB(const float* __restrict__ G, const float* __restrict__ oow,
                      const float* __restrict__ omix_p, unsigned short* __restrict__ MTB) {
  const int b = blockIdx.y, eb = blockIdx.x * 64, tid = threadIdx.x;
  __shared__ float g[OD][OD + 1];
  __shared__ float wl[64][65];
  for (int e2 = tid; e2 < OD * OD; e2 += 256) g[e2 >> 6][e2 & 63] = G[(size_t)b * OD * OD + e2];
  for (int e2 = tid; e2 < 64 * 64; e2 += 256) wl[e2 >> 6][e2 & 63] = oow[(size_t)(eb + (e2 >> 6)) * 64 + (e2 & 63)];
  __syncthreads();
  const float omix = omix_p[0];
  for (int o = tid; o < 4096; o += 256) {
    int el = o >> 6, d = o & 63;
    float s = 0.f;
    #pragma unroll
    for (int k = 0; k < 64; ++k) s = fmaf(g[d][k], wl[el][k], s);
    MTB[((size_t)b * DD + eb + el) * OD + d] = f2bf(omix * s);
  }
}

// ---------------- Kernel 3: MFMA main pass (v6) ----------------
// R9 v4 structure (TPB=256, 1 barrier/tile) + REGISTER double-buffered residual:
// tile t+1's 16 res loads are issued during tile t (even/odd unrolled bodies,
// named resA/resB arrays -> all indexing static, rule #20), so the combine
// never stalls on fresh loads and the barrier drain overlaps issued-early work.
#define STAGE_XH(BUF, TTOK)                                                          \
  if (stager) {                                                                      \
    const float4 v = *(const float4*)(x + xrow + (size_t)((TTOK) + stok) * DD + sd0);\
    unsigned int lo = (unsigned int)f2bf(v.x) | ((unsigned int)f2bf(v.y) << 16);     \
    unsigned int hi = (unsigned int)f2bf(v.z) | ((unsigned int)f2bf(v.w) << 16);     \
    *(uint2*)((char*)&(BUF)[0][0] + stok * 144 + sd0 * 2) = make_uint2(lo, hi);      \
  }

#define LOAD_RES(DST, TTOK)                                                          \
  _Pragma("unroll")                                                                  \
  for (int et = 0; et < 4; ++et) {                                                   \
    _Pragma("unroll")                                                                \
    for (int r = 0; r < 4; ++r)                                                      \
      DST[et][r] = x[xrow + (size_t)((TTOK) + g * 4 + r) * DD + ebase + et * 16 + c];\
  }

#define COMPUTE_TILE(XBUF, RES, PAR, TTOK)                                           \
  {                                                                                  \
    const char* xbB = (const char*)&(XBUF)[0][0];                                    \
    bf16x8 af0 = *(const bf16x8*)(xbB + c * 144 + 0 * 64 + g * 16);                  \
    bf16x8 af1 = *(const bf16x8*)(xbB + c * 144 + 1 * 64 + g * 16);                  \
    f32x4 acc[4];                                                                    \
    _Pragma("unroll")                                                                \
    for (int et = 0; et < 4; ++et) {                                                 \
      acc[et] = (f32x4){0.f, 0.f, 0.f, 0.f};                                         \
      acc[et] = __builtin_amdgcn_mfma_f32_16x16x32_bf16(af0, bf[et][0], acc[et], 0, 0, 0); \
      acc[et] = __builtin_amdgcn_mfma_f32_16x16x32_bf16(af1, bf[et][1], acc[et], 0, 0, 0); \
    }                                                                                \
    float p[4] = {0.f, 0.f, 0.f, 0.f};                                               \
    _Pragma("unroll")                                                                \
    for (int et = 0; et < 4; ++et) {                                                 \
      _Pragma("unroll")                                                              \
      for (int r = 0; r < 4; ++r) {                                                  \
        const float y = RES[et][r] + acc[et][r] + ce_r[et];                          \
        acc[et][r] = y;                                                              \
        p[r] = fmaf(y, y, p[r]);                                                     \
      }                                                                              \
    }                                                                                \
    _Pragma("unroll")                                                                \
    for (int mk = 1; mk < 16; mk <<= 1) {                                            \
      _Pragma("unroll")                                                              \
      for (int r = 0; r < 4; ++r) p[r] += __shfl_xor(p[r], mk, 64);                  \
    }                                                                                \
    if (c == 0) {                                                                    \
      _Pragma("unroll")                                                              \
      for (int r = 0; r < 4; ++r) red[PAR][g * 4 + r][w] = p[r];                     \
    }                                                                                \
    __syncthreads();                                                                 \
    float sc_r[4];                                                                   \
    _Pragma("unroll")                                                                \
    for (int r = 0; r < 4; ++r) {                                                    \
      const float4* rp = (const float4*)&red[PAR][g * 4 + r][0];                     \
      const float4 s0 = rp[0], s1 = rp[1], s2 = rp[2], s3 = rp[3];                   \
      const float s = s0.x + s0.y + s0.z + s0.w + s1.x + s1.y + s1.z + s1.w          \
                    + s2.x + s2.y + s2.z + s2.w + s3.x + s3.y + s3.z + s3.w;         \
      sc_r[r] = rsqrtf(s * (1.f / (float)DD) + 1e-6f);                               \
    }                                                                                \
    _Pragma("unroll")                                                                \
    for (int et = 0; et < 4; ++et) {                                                 \
      _Pragma("unroll")                                                              \
      for (int r = 0; r < 4; ++r) {                                                  \
        out[xrow + (size_t)((TTOK) + g * 4 + r) * DD + ebase + et * 16 + c] =        \
            acc[et][r] * sc_r[r] * nw_r[et];                                         \
      }                                                                              \
    }                                                                                \
  }

__global__ __launch_bounds__(1024)
void k_mfma(const float* __restrict__ x, const unsigned short* __restrict__ MTB,
            const float* __restrict__ cvec, const float* __restrict__ nw,
            float* __restrict__ out) {
  const int b = blockIdx.y;
  const int Tblk = blockIdx.x * TPB;
  const int tid = threadIdx.x;
  const int w = tid >> 6, lane = tid & 63;
  const int c = lane & 15, g = lane >> 4;
  const int ebase = w * 64;

  __shared__ unsigned short xh[2][TT][72];  // 144B rows: 64 d + 8 pad
  __shared__ float red[2][TT][20];          // padded rows: 2-way banks max

  bf16x8 bf[4][2];
  {
    const unsigned short* mp = MTB + ((size_t)b * DD + ebase + c) * OD + g * 8;
    #pragma unroll
    for (int et = 0; et < 4; ++et) {
      #pragma unroll
      for (int ks = 0; ks < 2; ++ks)
        bf[et][ks] = *(const bf16x8*)(mp + (size_t)et * 16 * OD + ks * 32);
    }
  }
  float ce_r[4], nw_r[4];
  #pragma unroll
  for (int et = 0; et < 4; ++et) {
    ce_r[et] = cvec[(size_t)b * DD + ebase + et * 16 + c];
    nw_r[et] = nw[ebase + et * 16 + c];
  }

  const size_t xrow = ((size_t)b * LL + Tblk) * DD;
  const int stok = tid >> 4, sd0 = (tid & 15) * 4;
  const bool stager = (tid < 256);

  float resA[4][4], resB[4][4];

  // prologue: stage tile 0 + issue its residual loads (drained at first barrier)
  STAGE_XH(xh[0], 0)
  LOAD_RES(resA, 0)
  __syncthreads();

  #pragma unroll 1
  for (int it = 0; it < TPB / (2 * TT); ++it) {
    const int te = it * 2 * TT;       // even tile tokens
    const int to = te + TT;           // odd tile tokens
    const int tn = te + 2 * TT;       // next even tile tokens
    // ---- EVEN tile: uses xh[0]/resA; stages xh[1]; prefetches resB ----
    STAGE_XH(xh[1], to)
    LOAD_RES(resB, to)
    COMPUTE_TILE(xh[0], resA, 0, te)
    // ---- ODD tile: uses xh[1]/resB; stages xh[0]; prefetches resA ----
    if (it + 1 < TPB / (2 * TT)) {
      STAGE_XH(xh[0], tn)
      LOAD_RES(resA, tn)
    }
    COMPUTE_TILE(xh[1], resB, 1, to)
  }
}

extern "C" void kernel_launch(void* const* d_in, const int* in_sizes, int n_in,
                              void* d_out, int out_size, void* d_ws, size_t ws_size,
                              hipStream_t stream) {
  (void)in_sizes; (void)n_in; (void)out_size; (void)ws_size;
  const float* x    = (const float*)d_in[0];
  const float* opw  = (const float*)d_in[1];
  const float* opb  = (const float*)d_in[2];
  const float* oow  = (const float*)d_in[3];
  const float* oob  = (const float*)d_in[4];
  const float* viw  = (const float*)d_in[5];
  const float* vib  = (const float*)d_in[6];
  const float* vow  = (const float*)d_in[7];
  const float* vob  = (const float*)d_in[8];
  const float* cb   = (const float*)d_in[9];
  const float* omix = (const float*)d_in[10];
  const float* vmix = (const float*)d_in[11];
  const float* nw   = (const float*)d_in[12];
  float* out = (float*)d_out;

  float* ws      = (float*)d_ws;
  float* partial = ws;                 // 1048576 floats
  float* hm      = ws + 1048576;       // 16384
  float* params  = ws + 1064960;       // 32256
  float* vqi_g   = ws + 1097216;       // 1024
  float* G       = ws + 1098240;       // 65536
  unsigned short* MTB = (unsigned short*)(ws + 1163776);  // 1M ushort
  float* cvec    = ws + 1688064;       // 16384

  k_partial<<<dim3(NCHUNK, BB), 256, 0, stream>>>(x, partial);
  k_mean<<<BB, 256, 0, stream>>>(partial, hm);
  k_params<<<NROW / 4, 256, 0, stream>>>(hm, opw, opb, viw, vib, params, vqi_g);
  k_perb<<<BB, 256, 0, stream>>>(params, vqi_g, cb, oob, vow, vob, omix, vmix, G, cvec);
  k_MTB<<<dim3(16, BB), 256, 0, stream>>>(G, oow, omix, MTB);
  k_mfma<<<dim3(LL / TPB, BB), 1024, 0, stream>>>(x, MTB, cvec, nw, out);
}